// Round 1
// baseline (385.198 us; speedup 1.0000x reference)
//
#include <hip/hip_runtime.h>
#include <math.h>

// Problem constants (fixed by setup_inputs)
#define NB 4
#define NH 64
#define NW 64
#define NS 64            // samples per ray
#define HID 128
#define POS_IN 63
#define DIR_IN 27
#define TOTAL_PARAMS 8789
// param offsets per batch row
#define OFF_POSW 0       // 128*63
#define OFF_POSB 8064    // 128
#define OFF_SIGW 8192    // 128
#define OFF_SIGB 8320    // 1
#define OFF_COLW 8321    // 3*155
#define OFF_COLB 8786    // 3

// Accurate sin/cos of a (possibly large, |arg| < ~2^14 rad) fp32 argument.
// Cody-Waite: pi = PI_HI(8-bit mantissa, exact) + PI_MID(11-bit) + PI_LO.
// n up to ~2^13 -> n*PI_HI and n*PI_MID products are exact in fp32.
__device__ __forceinline__ void sincos_acc(float arg, float& s, float& c) {
    const float INV_PI = 0.31830988618379067f;
    float nf = rintf(arg * INV_PI);
    float r = fmaf(nf, -3.140625f, arg);        // PI_HI = 201/64, 8-bit mantissa
    r = fmaf(nf, -9.675025940e-4f, r);          // PI_MID, 11-bit mantissa
    r = fmaf(nf, -1.509957880e-7f, r);          // PI_LO
    float ss = __sinf(r);                       // |r| <= pi/2: accurate
    float cc = __cosf(r);
    int n = (int)nf;
    if (n & 1) { ss = -ss; cc = -cc; }
    s = ss; c = cc;
}

__launch_bounds__(256, 4)
__global__ void nerf_render_kernel(const float* __restrict__ params,
                                   const float* __restrict__ poses,
                                   const float* __restrict__ Ks,
                                   float* __restrict__ out)
{
    // LDS staging of per-batch MLP weights.
    __shared__ float wlds[HID * 64];     // pos_w padded 63->64, row h at h*64, pad=0
    __shared__ float comb[HID * 4];      // [h][4] = {sig_w[h], col_w[0][h], col_w[1][h], col_w[2][h]}
    __shared__ float posb[HID];
    __shared__ float cwd[DIR_IN * 3 + 3]; // col_w dir part: [k][c], k=0..26
    __shared__ float extra[4];           // sig_b, col_b[0..2]

    const int tid  = threadIdx.x;
    const int lane = tid & 63;                   // sample index along ray
    const int ray  = blockIdx.x * 4 + (tid >> 6);
    const int b    = ray >> 12;                  // 4096 rays per batch
    const int p    = ray & 4095;                 // pixel index i*W+j
    const int i    = p >> 6;
    const int j    = p & 63;

    const float* pb = params + b * TOTAL_PARAMS;

    // ---- stage weights to LDS ----
    for (int k = tid; k < HID * POS_IN; k += 256) {
        int h = k / 63, d = k - h * 63;
        wlds[h * 64 + d] = pb[OFF_POSW + k];
    }
    if (tid < HID) {
        wlds[tid * 64 + 63] = 0.0f;              // zero pad (poison-safe)
        posb[tid] = pb[OFF_POSB + tid];
        comb[tid * 4 + 0] = pb[OFF_SIGW + tid];
    }
    for (int k = tid; k < 3 * 155; k += 256) {
        int c = k / 155, q = k - c * 155;
        float v = pb[OFF_COLW + k];
        if (q < HID) comb[q * 4 + 1 + c] = v;
        else cwd[(q - HID) * 3 + c] = v;
    }
    if (tid == 0) extra[0] = pb[OFF_SIGB];
    if (tid < 3) extra[1 + tid] = pb[OFF_COLB + tid];
    __syncthreads();

    // ---- ray setup ----
    const float* Kb = Ks + b * 9;
    float fx = Kb[0], cx = Kb[2], fy = Kb[4], cy = Kb[5];
    const float* Pb = poses + b * 16;
    float dcx = ((float)j - cx) / fx;
    float dcy = -(((float)i - cy) / fy);
    float dcz = -1.0f;
    float dx = Pb[0] * dcx + Pb[1] * dcy + Pb[2]  * dcz;
    float dy = Pb[4] * dcx + Pb[5] * dcy + Pb[6]  * dcz;
    float dz = Pb[8] * dcx + Pb[9] * dcy + Pb[10] * dcz;
    float ox = Pb[3], oy = Pb[7], oz = Pb[11];

    float t0 = (float)lane * (1.0f / 63.0f);
    float z  = 0.1f * (1.0f - t0) + 10.0f * t0;
    float t1 = (float)(lane + 1) * (1.0f / 63.0f);
    float z1 = 0.1f * (1.0f - t1) + 10.0f * t1;
    float dist = (lane == 63) ? 1e10f : (z1 - z);

    float px = ox + dx * z, py = oy + dy * z, pz = oz + dz * z;

    // ---- positional encoding into registers (compile-time indices only) ----
    const float PI_F = 3.14159274101257324f;     // fl(pi), matches jnp weak-typed pi
    float pe[64];
    pe[0] = px; pe[1] = py; pe[2] = pz;
    pe[63] = 0.0f;
    #pragma unroll
    for (int f = 0; f < 10; f++) {
        float freq = PI_F * (float)(1 << f);     // exact pow2 scaling = reference freqs
        float s0, c0, s1, c1, s2, c2;
        sincos_acc(px * freq, s0, c0);
        sincos_acc(py * freq, s1, c1);
        sincos_acc(pz * freq, s2, c2);
        pe[3 + f * 6 + 0] = s0; pe[3 + f * 6 + 1] = s1; pe[3 + f * 6 + 2] = s2;
        pe[3 + f * 6 + 3] = c0; pe[3 + f * 6 + 4] = c1; pe[3 + f * 6 + 5] = c2;
    }

    // ---- color accumulators: bias + direction-encoding part (shared per ray) ----
    float cacc0 = extra[1], cacc1 = extra[2], cacc2 = extra[3];
    {
        float dvx = dx, dvy = dy, dvz = dz;
        cacc0 += cwd[0] * dvx + cwd[3] * dvy + cwd[6] * dvz;
        cacc1 += cwd[1] * dvx + cwd[4] * dvy + cwd[7] * dvz;
        cacc2 += cwd[2] * dvx + cwd[5] * dvy + cwd[8] * dvz;
        #pragma unroll
        for (int f = 0; f < 4; f++) {
            float freq = PI_F * (float)(1 << f);
            float sv[3], cv[3];
            sincos_acc(dvx * freq, sv[0], cv[0]);
            sincos_acc(dvy * freq, sv[1], cv[1]);
            sincos_acc(dvz * freq, sv[2], cv[2]);
            #pragma unroll
            for (int d0 = 0; d0 < 3; d0++) {
                int ks = 3 + f * 6 + d0;
                int kc = ks + 3;
                cacc0 += cwd[ks * 3 + 0] * sv[d0]; 
                cacc1 += cwd[ks * 3 + 1] * sv[d0];
                cacc2 += cwd[ks * 3 + 2] * sv[d0];
                cacc0 += cwd[kc * 3 + 0] * cv[d0];
                cacc1 += cwd[kc * 3 + 1] * cv[d0];
                cacc2 += cwd[kc * 3 + 2] * cv[d0];
            }
        }
    }

    // ---- main MLP loop: 128 hidden units, weights broadcast from LDS ----
    float sacc = extra[0];
    const float4* wlds4 = (const float4*)wlds;
    const float4* comb4 = (const float4*)comb;
    for (int h = 0; h < HID; h++) {
        float4 sc = comb4[h];
        const float4* wr = wlds4 + h * 16;
        float a0 = posb[h], a1 = 0.0f, a2 = 0.0f, a3 = 0.0f;  // 4 chains for ILP
        #pragma unroll
        for (int q = 0; q < 16; q++) {
            float4 w4 = wr[q];
            a0 = fmaf(w4.x, pe[q * 4 + 0], a0);
            a1 = fmaf(w4.y, pe[q * 4 + 1], a1);
            a2 = fmaf(w4.z, pe[q * 4 + 2], a2);
            a3 = fmaf(w4.w, pe[q * 4 + 3], a3);
        }
        float hv = fmaxf((a0 + a1) + (a2 + a3), 0.0f);
        sacc  = fmaf(sc.x, hv, sacc);
        cacc0 = fmaf(sc.y, hv, cacc0);
        cacc1 = fmaf(sc.z, hv, cacc1);
        cacc2 = fmaf(sc.w, hv, cacc2);
    }

    // ---- volume rendering: wave-level scan over the 64 samples of this ray ----
    float alpha = 1.0f - expf(-fmaxf(sacc, 0.0f) * dist);
    float tr = 1.0f - alpha + 1e-10f;
    float prod = tr;
    #pragma unroll
    for (int off = 1; off < 64; off <<= 1) {
        float up = __shfl_up(prod, off);
        if (lane >= off) prod *= up;
    }
    float T = __shfl_up(prod, 1);
    if (lane == 0) T = 1.0f;
    float w = alpha * T;

    float r = 1.0f / (1.0f + expf(-cacc0));
    float g = 1.0f / (1.0f + expf(-cacc1));
    float bl = 1.0f / (1.0f + expf(-cacc2));

    float wr_ = w * r, wg_ = w * g, wb_ = w * bl, wz_ = w * z, wa_ = w;
    #pragma unroll
    for (int off = 32; off >= 1; off >>= 1) {
        wr_ += __shfl_xor(wr_, off);
        wg_ += __shfl_xor(wg_, off);
        wb_ += __shfl_xor(wb_, off);
        wz_ += __shfl_xor(wz_, off);
        wa_ += __shfl_xor(wa_, off);
    }

    if (lane == 0) {
        float bg = 1.0f - wa_;
        // rgb_img: [B,3,H,W] then depth [B,1,H,W] then acc [B,1,H,W], flat
        out[(b * 3 + 0) * 4096 + p] = wr_ + bg;
        out[(b * 3 + 1) * 4096 + p] = wg_ + bg;
        out[(b * 3 + 2) * 4096 + p] = wb_ + bg;
        out[NB * 3 * 4096 + b * 4096 + p] = wz_;
        out[NB * 4 * 4096 + b * 4096 + p] = wa_;
    }
}

extern "C" void kernel_launch(void* const* d_in, const int* in_sizes, int n_in,
                              void* d_out, int out_size, void* d_ws, size_t ws_size,
                              hipStream_t stream) {
    const float* params = (const float*)d_in[0];
    const float* poses  = (const float*)d_in[1];
    const float* Ks     = (const float*)d_in[2];
    float* out = (float*)d_out;
    // 4 batches * 4096 rays / 4 rays-per-block = 4096 blocks, 256 threads
    nerf_render_kernel<<<dim3(4096), dim3(256), 0, stream>>>(params, poses, Ks, out);
}